// Round 1
// 13119.249 us; speedup vs baseline: 7.1931x; 7.1931x over previous
//
#include <hip/hip_runtime.h>
#include <hip/hip_bf16.h>

typedef __attribute__((ext_vector_type(8))) __bf16 bf16x8;
typedef __attribute__((ext_vector_type(4))) float f32x4;
typedef __attribute__((ext_vector_type(4))) int i32x4;

constexpr int B_N = 64;
constexpr int T_N = 1024;
constexpr int H_N = 512;
constexpr long long BT_N = (long long)B_N * T_N;   // 65536

// ---------------------------------------------------------------------------
// fp32 -> bf16 convert (4 elems/thread, grid-stride)
// ---------------------------------------------------------------------------
__global__ void cvt_f32_bf16(const float* __restrict__ src,
                             __hip_bfloat16* __restrict__ dst, long long n4)
{
    long long i = (long long)blockIdx.x * blockDim.x + threadIdx.x;
    long long stride = (long long)gridDim.x * blockDim.x;
    for (; i < n4; i += stride) {
        float4 v = ((const float4*)src)[i];
        __hip_bfloat16* d = dst + i * 4;
        d[0] = __float2bfloat16(v.x);
        d[1] = __float2bfloat16(v.y);
        d[2] = __float2bfloat16(v.z);
        d[3] = __float2bfloat16(v.w);
    }
}

// ---------------------------------------------------------------------------
// bf16 MFMA GEMM: C[M,N] = act(A[M,K] @ W[N,K]^T + bias)  (unchanged)
// ---------------------------------------------------------------------------
__device__ inline void store_val(float* p, float v) { *p = v; }
__device__ inline void store_val(__hip_bfloat16* p, float v) { *p = __float2bfloat16(v); }

template <typename OutT, bool RELU>
__global__ __launch_bounds__(256)
void mfma_gemm(const __hip_bfloat16* __restrict__ A,
               const __hip_bfloat16* __restrict__ W,
               const float* __restrict__ bias,
               OutT* __restrict__ C, int M, int N, int K)
{
    constexpr int LDT = 72;
    __shared__ __hip_bfloat16 Asl[128 * LDT];
    __shared__ __hip_bfloat16 Bsl[128 * LDT];

    const int tid  = threadIdx.x;
    const int wv   = tid >> 6;
    const int lane = tid & 63;
    const int quad = lane >> 4;
    const int l16  = lane & 15;
    const int bm = blockIdx.y, bn = blockIdx.x;
    const int m0w = (wv & 1) * 64;
    const int n0w = (wv >> 1) * 64;

    f32x4 acc[4][4] = {};

    for (int k0 = 0; k0 < K; k0 += 64) {
        __syncthreads();
#pragma unroll
        for (int i = 0; i < 4; ++i) {
            int c = tid + i * 256;
            int row = c >> 3, ch = c & 7;
            bf16x8 va = *(const bf16x8*)(A + (size_t)(bm * 128 + row) * K + k0 + ch * 8);
            bf16x8 vb = *(const bf16x8*)(W + (size_t)(bn * 128 + row) * K + k0 + ch * 8);
            *(bf16x8*)(Asl + row * LDT + ch * 8) = va;
            *(bf16x8*)(Bsl + row * LDT + ch * 8) = vb;
        }
        __syncthreads();
#pragma unroll
        for (int kc = 0; kc < 2; ++kc) {
            const int koff = kc * 32 + quad * 8;
            bf16x8 af[4], bfr[4];
#pragma unroll
            for (int mt = 0; mt < 4; ++mt)
                af[mt] = *(const bf16x8*)(Asl + (m0w + mt * 16 + l16) * LDT + koff);
#pragma unroll
            for (int nt = 0; nt < 4; ++nt)
                bfr[nt] = *(const bf16x8*)(Bsl + (n0w + nt * 16 + l16) * LDT + koff);
#pragma unroll
            for (int mt = 0; mt < 4; ++mt)
#pragma unroll
                for (int nt = 0; nt < 4; ++nt)
                    acc[mt][nt] = __builtin_amdgcn_mfma_f32_16x16x32_bf16(
                        af[mt], bfr[nt], acc[mt][nt], 0, 0, 0);
        }
    }

#pragma unroll
    for (int nt = 0; nt < 4; ++nt) {
        const int col = bn * 128 + n0w + nt * 16 + l16;
        const float bv = bias[col];
#pragma unroll
        for (int mt = 0; mt < 4; ++mt) {
#pragma unroll
            for (int rg = 0; rg < 4; ++rg) {
                const int row = bm * 128 + m0w + mt * 16 + quad * 4 + rg;
                float v = acc[mt][nt][rg] + bv;
                if (RELU) v = fmaxf(v, 0.f);
                store_val(C + (size_t)row * N + col, v);
            }
        }
    }
}

// ---------------------------------------------------------------------------
// Batch-group GRU scan, no grid.sync.
//   grid = 32 blocks x 384 thr. block = (grp = bx>>3) x (slc = bx&7).
//   grp: 16 batch rows [grp*16, +16) — groups are fully independent.
//   slc: 64 hidden cols [slc*64, +64) — W_hh slice (192 gate-cols) in VGPRs
//        (2 N-tiles x 16 k-chunks = 128 VGPRs per wave, 6 waves: g = wv>>1,
//         jt = wv&1).
//   h_{t-1} for the group's 16 rows lives in LDS (row stride 1040 B ->
//   conflict-floor b128 A-fragment reads). Cross-slice h exchange goes
//   through y with sc0/sc1 (device-coherent, bypasses non-coherent L2s);
//   per-(grp,t) arrival counter + relaxed agent atomics replace grid.sync
//   (no L2 writeback fences on the 1024-step critical path).
// ---------------------------------------------------------------------------
__device__ inline float u2f(unsigned u) { union { unsigned u; float f; } c; c.u = u; return c.f; }
__device__ inline float sigm(float x) { return 1.f / (1.f + __expf(-x)); }

__global__ __launch_bounds__(384)
void gru_scan_grp(const __hip_bfloat16* __restrict__ gi,   // [64][1024][1536]
                  const __hip_bfloat16* __restrict__ whh,  // [1536][512]
                  const float* __restrict__ bhh,           // [1536]
                  __hip_bfloat16* __restrict__ y,          // [64][1024][512]
                  unsigned* __restrict__ bar)              // [4 grp][1024 t]
{
    constexpr int LROW = 1040;                 // bytes per LDS h row (512*2 + 16 pad)
    __shared__ __align__(16) char hsl[16 * LROW];
    __shared__ float ghl[3][16][66];

    const int tid  = threadIdx.x;
    const int wv   = tid >> 6;                 // 0..5
    const int lane = tid & 63;
    const int quad = lane >> 4;
    const int l16  = lane & 15;
    const int grp  = blockIdx.x >> 3;          // batch group 0..3
    const int slc  = blockIdx.x & 7;           // hidden slice 0..7
    const int j0   = slc * 64;
    const int m0   = grp * 16;
    const int g    = wv >> 1;                  // gate 0..2
    const int jt   = wv & 1;
    unsigned* cnt = bar + grp * 1024;

    // W_hh fragments, VGPR-resident for all 1024 steps
    const int colg = g * 512 + j0 + jt * 32;
    bf16x8 bfrag[2][16];
#pragma unroll
    for (int nt = 0; nt < 2; ++nt)
#pragma unroll
        for (int kc = 0; kc < 16; ++kc)
            bfrag[nt][kc] = *(const bf16x8*)(whh + (size_t)(colg + nt * 16 + l16) * 512
                                             + kc * 32 + quad * 8);

    // zero h state (t=0 reads h=0)
    for (int c = tid; c < 16 * LROW / 16; c += 384)
        ((i32x4*)hsl)[c] = (i32x4)0;

    // combine-thread setup (threads 0..255): item = (p in 0..1, um, jp)
    const int um = tid >> 5;                   // 0..7
    const int jp = tid & 31;                   // j-pair index
    float br0 = 0, br1 = 0, bz0 = 0, bz1 = 0, bn0 = 0, bn1 = 0;
    const __hip_bfloat16* gip[2] = {nullptr, nullptr};
    __hip_bfloat16* ysp[2] = {nullptr, nullptr};
    int hof[2] = {0, 0};
    if (tid < 256) {
        const int jg = j0 + 2 * jp;            // global hidden col (even)
        br0 = bhh[jg];         br1 = bhh[jg + 1];
        bz0 = bhh[512 + jg];   bz1 = bhh[512 + jg + 1];
        bn0 = bhh[1024 + jg];  bn1 = bhh[1024 + jg + 1];
#pragma unroll
        for (int p = 0; p < 2; ++p) {
            const int mg = m0 + p * 8 + um;
            gip[p] = gi + (size_t)mg * 1024 * 1536 + jg;
            ysp[p] = y  + (size_t)mg * 1024 * 512  + jg;
            hof[p] = (p * 8 + um) * LROW + jg * 2;
        }
    }

    // refill setup (threads 0..255): 4 x 16B chunks covering 16 rows x 1024 B
    const int mr  = tid >> 6;                  // 0..3
    const int bof = (tid & 63) * 16;
    const char* yre[4] = {nullptr, nullptr, nullptr, nullptr};
    int dst[4] = {0, 0, 0, 0};
    if (tid < 256) {
#pragma unroll
        for (int q = 0; q < 4; ++q) {
            const int m = mr + q * 4;
            yre[q] = (const char*)(y + (size_t)(m0 + m) * 1024 * 512) + bof;
            dst[q] = m * LROW + bof;
        }
    }

    const int abase = l16 * LROW + quad * 16;  // A-fragment base in LDS

    __syncthreads();

#pragma unroll 1
    for (int t = 0; t < 1024; ++t) {
        // gi preload (plain cached loads; latency hidden under MFMA)
        unsigned pr[2], pz[2], pn[2];
        if (tid < 256) {
#pragma unroll
            for (int p = 0; p < 2; ++p) {
                pr[p] = *(const unsigned*)(gip[p]);
                pz[p] = *(const unsigned*)(gip[p] + 512);
                pn[p] = *(const unsigned*)(gip[p] + 1024);
                gip[p] += 1536;
            }
        }

        // gh = h_{t-1} @ Whh_slice^T   (A from LDS, B from VGPRs)
        f32x4 a0 = {}, a1 = {};
        if (t > 0) {
#pragma unroll
            for (int kc = 0; kc < 16; ++kc) {
                bf16x8 af = *(const bf16x8*)(hsl + abase + kc * 64);
                a0 = __builtin_amdgcn_mfma_f32_16x16x32_bf16(af, bfrag[0][kc], a0, 0, 0, 0);
                a1 = __builtin_amdgcn_mfma_f32_16x16x32_bf16(af, bfrag[1][kc], a1, 0, 0, 0);
            }
        }
#pragma unroll
        for (int rg = 0; rg < 4; ++rg) {
            ghl[g][quad * 4 + rg][jt * 32 + l16]      = a0[rg];
            ghl[g][quad * 4 + rg][jt * 32 + 16 + l16] = a1[rg];
        }
        __syncthreads();

        // gate combine + h_t write (device-coherent dword stores)
        if (tid < 256) {
#pragma unroll
            for (int p = 0; p < 2; ++p) {
                const int m = p * 8 + um;
                const float2 gr = *(const float2*)&ghl[0][m][jp * 2];
                const float2 gz = *(const float2*)&ghl[1][m][jp * 2];
                const float2 gn = *(const float2*)&ghl[2][m][jp * 2];
                const unsigned hpk = *(const unsigned*)(hsl + hof[p]);
                const float hp0 = u2f(hpk << 16), hp1 = u2f(hpk & 0xffff0000u);
                const float r0 = sigm(u2f(pr[p] << 16)         + gr.x + br0);
                const float r1 = sigm(u2f(pr[p] & 0xffff0000u) + gr.y + br1);
                const float z0 = sigm(u2f(pz[p] << 16)         + gz.x + bz0);
                const float z1 = sigm(u2f(pz[p] & 0xffff0000u) + gz.y + bz1);
                const float n0 = tanhf(u2f(pn[p] << 16)         + r0 * (gn.x + bn0));
                const float n1 = tanhf(u2f(pn[p] & 0xffff0000u) + r1 * (gn.y + bn1));
                const float h0 = (1.f - z0) * n0 + z0 * hp0;
                const float h1 = (1.f - z1) * n1 + z1 * hp1;
                const unsigned outv =
                    (unsigned)__bfloat16_as_ushort(__float2bfloat16(h0)) |
                    ((unsigned)__bfloat16_as_ushort(__float2bfloat16(h1)) << 16);
                asm volatile("global_store_dword %0, %1, off sc0 sc1"
                             :: "v"((void*)ysp[p]), "v"(outv) : "memory");
                ysp[p] += 512;
            }
        }
        __syncthreads();   // drains vmcnt: all slice stores visible at L3

        // group barrier: per-t counter, relaxed agent atomics (no cache fences)
        if (tid == 0) {
            __hip_atomic_fetch_add(&cnt[t], 1u, __ATOMIC_RELAXED, __HIP_MEMORY_SCOPE_AGENT);
            while (__hip_atomic_load(&cnt[t], __ATOMIC_RELAXED, __HIP_MEMORY_SCOPE_AGENT) < 8u)
                __builtin_amdgcn_s_sleep(2);
        }
        __syncthreads();

        // refill LDS h with the full 512-col h_t (device-coherent loads)
        if (t < 1023) {
            if (tid < 256) {
                i32x4 v0, v1, v2, v3;
                asm volatile(
                    "global_load_dwordx4 %0, %4, off sc0 sc1\n\t"
                    "global_load_dwordx4 %1, %5, off sc0 sc1\n\t"
                    "global_load_dwordx4 %2, %6, off sc0 sc1\n\t"
                    "global_load_dwordx4 %3, %7, off sc0 sc1\n\t"
                    "s_waitcnt vmcnt(0)"
                    : "=&v"(v0), "=&v"(v1), "=&v"(v2), "=&v"(v3)
                    : "v"((const void*)yre[0]), "v"((const void*)yre[1]),
                      "v"((const void*)yre[2]), "v"((const void*)yre[3])
                    : "memory");
                *(i32x4*)(hsl + dst[0]) = v0;
                *(i32x4*)(hsl + dst[1]) = v1;
                *(i32x4*)(hsl + dst[2]) = v2;
                *(i32x4*)(hsl + dst[3]) = v3;
                yre[0] += 1024; yre[1] += 1024; yre[2] += 1024; yre[3] += 1024;
            }
            __syncthreads();
        }
    }
}

// ---------------------------------------------------------------------------
// Host-side launch
// ---------------------------------------------------------------------------
extern "C" void kernel_launch(void* const* d_in, const int* in_sizes, int n_in,
                              void* d_out, int out_size, void* d_ws, size_t ws_size,
                              hipStream_t stream)
{
    const float* x    = (const float*)d_in[0];
    const float* w_in = (const float*)d_in[1];
    const float* b_in = (const float*)d_in[2];
    const float* w_ih = (const float*)d_in[3];
    const float* w_hh = (const float*)d_in[4];
    const float* b_ih = (const float*)d_in[5];
    const float* b_hh = (const float*)d_in[6];
    const float* w_o1 = (const float*)d_in[7];
    const float* b_o1 = (const float*)d_in[8];
    const float* w_o2 = (const float*)d_in[9];
    const float* b_o2 = (const float*)d_in[10];
    float* out = (float*)d_out;

    char* ws = (char*)d_ws;
    const size_t GI_BYTES  = (size_t)BT_N * 1536 * 2;  // 201,326,592
    const size_t ACT_BYTES = (size_t)BT_N * 512 * 2;   //  67,108,864
    const size_t WT_BYTES  = (size_t)7077888 * 2;      //  14,155,776
    __hip_bfloat16* gi   = (__hip_bfloat16*)ws;
    __hip_bfloat16* act  = (__hip_bfloat16*)(ws + GI_BYTES);
    __hip_bfloat16* wbf  = (__hip_bfloat16*)(ws + GI_BYTES + ACT_BYTES);
    unsigned*       bar  = (unsigned*)(ws + GI_BYTES + ACT_BYTES + WT_BYTES); // 64 KiB
    __hip_bfloat16* xbf  = gi;   // alias: dead before gi written
    __hip_bfloat16* tmp  = gi;   // alias: MLP intermediate

    __hip_bfloat16* w_in_bf = wbf;
    __hip_bfloat16* w_ih_bf = wbf + 262144;
    __hip_bfloat16* w_hh_bf = w_ih_bf + 3145728;
    __hip_bfloat16* w_o1_bf = w_hh_bf + 3145728;
    __hip_bfloat16* w_o2_bf = w_o1_bf + 262144;

    // scan barrier counters: [4 layers][4 groups][1024 t]
    hipMemsetAsync(bar, 0, (size_t)4 * 4 * 1024 * sizeof(unsigned), stream);

    cvt_f32_bf16<<<256, 256, 0, stream>>>(w_in, w_in_bf, 262144 / 4);
    cvt_f32_bf16<<<1024, 256, 0, stream>>>(w_ih, w_ih_bf, 3145728 / 4);
    cvt_f32_bf16<<<1024, 256, 0, stream>>>(w_hh, w_hh_bf, 3145728 / 4);
    cvt_f32_bf16<<<256, 256, 0, stream>>>(w_o1, w_o1_bf, 262144 / 4);
    cvt_f32_bf16<<<256, 256, 0, stream>>>(w_o2, w_o2_bf, 262144 / 4);
    cvt_f32_bf16<<<4096, 256, 0, stream>>>(x, xbf, BT_N * 512 / 4);

    const int M = (int)BT_N;

    mfma_gemm<__hip_bfloat16, true><<<dim3(4, 512), 256, 0, stream>>>(
        xbf, w_in_bf, b_in, act, M, 512, 512);

    for (int l = 0; l < 4; ++l) {
        const __hip_bfloat16* wih_l = w_ih_bf + (size_t)l * 1536 * 512;
        const __hip_bfloat16* whh_l = w_hh_bf + (size_t)l * 1536 * 512;
        const float* bih_l = b_ih + (size_t)l * 1536;
        const float* bhh_l = b_hh + (size_t)l * 1536;

        mfma_gemm<__hip_bfloat16, false><<<dim3(12, 512), 256, 0, stream>>>(
            act, wih_l, bih_l, gi, M, 1536, 512);

        gru_scan_grp<<<dim3(32), dim3(384), 0, stream>>>(
            gi, whh_l, bhh_l, act, bar + (size_t)l * 4096);
    }

    mfma_gemm<__hip_bfloat16, true><<<dim3(4, 512), 256, 0, stream>>>(
        act, w_o1_bf, b_o1, tmp, M, 512, 512);
    mfma_gemm<float, false><<<dim3(4, 512), 256, 0, stream>>>(
        tmp, w_o2_bf, b_o2, out, M, 512, 512);
}

// Round 3
// 11668.794 us; speedup vs baseline: 8.0872x; 1.1243x over previous
//
#include <hip/hip_runtime.h>
#include <hip/hip_bf16.h>

typedef __attribute__((ext_vector_type(8))) __bf16 bf16x8;
typedef __attribute__((ext_vector_type(4))) float f32x4;
typedef __attribute__((ext_vector_type(4))) int i32x4;

constexpr int B_N = 64;
constexpr int T_N = 1024;
constexpr long long BT_N = (long long)B_N * T_N;   // 65536

// ---------------------------------------------------------------------------
// fp32 -> bf16 convert (4 elems/thread, grid-stride)
// ---------------------------------------------------------------------------
__global__ void cvt_f32_bf16(const float* __restrict__ src,
                             __hip_bfloat16* __restrict__ dst, long long n4)
{
    long long i = (long long)blockIdx.x * blockDim.x + threadIdx.x;
    long long stride = (long long)gridDim.x * blockDim.x;
    for (; i < n4; i += stride) {
        float4 v = ((const float4*)src)[i];
        __hip_bfloat16* d = dst + i * 4;
        d[0] = __float2bfloat16(v.x);
        d[1] = __float2bfloat16(v.y);
        d[2] = __float2bfloat16(v.z);
        d[3] = __float2bfloat16(v.w);
    }
}

// ---------------------------------------------------------------------------
// bf16 MFMA GEMM: C[M,N] = act(A[M,K] @ W[N,K]^T + bias)  (unchanged)
// ---------------------------------------------------------------------------
__device__ inline void store_val(float* p, float v) { *p = v; }
__device__ inline void store_val(__hip_bfloat16* p, float v) { *p = __float2bfloat16(v); }

template <typename OutT, bool RELU>
__global__ __launch_bounds__(256)
void mfma_gemm(const __hip_bfloat16* __restrict__ A,
               const __hip_bfloat16* __restrict__ W,
               const float* __restrict__ bias,
               OutT* __restrict__ C, int M, int N, int K)
{
    constexpr int LDT = 72;
    __shared__ __hip_bfloat16 Asl[128 * LDT];
    __shared__ __hip_bfloat16 Bsl[128 * LDT];

    const int tid  = threadIdx.x;
    const int wv   = tid >> 6;
    const int lane = tid & 63;
    const int quad = lane >> 4;
    const int l16  = lane & 15;
    const int bm = blockIdx.y, bn = blockIdx.x;
    const int m0w = (wv & 1) * 64;
    const int n0w = (wv >> 1) * 64;

    f32x4 acc[4][4] = {};

    for (int k0 = 0; k0 < K; k0 += 64) {
        __syncthreads();
#pragma unroll
        for (int i = 0; i < 4; ++i) {
            int c = tid + i * 256;
            int row = c >> 3, ch = c & 7;
            bf16x8 va = *(const bf16x8*)(A + (size_t)(bm * 128 + row) * K + k0 + ch * 8);
            bf16x8 vb = *(const bf16x8*)(W + (size_t)(bn * 128 + row) * K + k0 + ch * 8);
            *(bf16x8*)(Asl + row * LDT + ch * 8) = va;
            *(bf16x8*)(Bsl + row * LDT + ch * 8) = vb;
        }
        __syncthreads();
#pragma unroll
        for (int kc = 0; kc < 2; ++kc) {
            const int koff = kc * 32 + quad * 8;
            bf16x8 af[4], bfr[4];
#pragma unroll
            for (int mt = 0; mt < 4; ++mt)
                af[mt] = *(const bf16x8*)(Asl + (m0w + mt * 16 + l16) * LDT + koff);
#pragma unroll
            for (int nt = 0; nt < 4; ++nt)
                bfr[nt] = *(const bf16x8*)(Bsl + (n0w + nt * 16 + l16) * LDT + koff);
#pragma unroll
            for (int mt = 0; mt < 4; ++mt)
#pragma unroll
                for (int nt = 0; nt < 4; ++nt)
                    acc[mt][nt] = __builtin_amdgcn_mfma_f32_16x16x32_bf16(
                        af[mt], bfr[nt], acc[mt][nt], 0, 0, 0);
        }
    }

#pragma unroll
    for (int nt = 0; nt < 4; ++nt) {
        const int col = bn * 128 + n0w + nt * 16 + l16;
        const float bv = bias[col];
#pragma unroll
        for (int mt = 0; mt < 4; ++mt) {
#pragma unroll
            for (int rg = 0; rg < 4; ++rg) {
                const int row = bm * 128 + m0w + mt * 16 + quad * 4 + rg;
                float v = acc[mt][nt][rg] + bv;
                if (RELU) v = fmaxf(v, 0.f);
                store_val(C + (size_t)row * N + col, v);
            }
        }
    }
}

// ---------------------------------------------------------------------------
// Fully fused 4-layer pipelined GRU scan.
//   grid = 256 blocks x 384 thr: layer = bx>>6 (launched first), grp =
//   (bx>>4)&3 (16 batch rows), slc = bx&15 (32 hidden cols).
//   Wave wv: gate g = wv>>1, j-tile jt = wv&1 -> 16 gate-cols. Each wave
//   holds W_ih AND W_hh fragments in VGPRs (128 regs) and computes both the
//   input-side and hidden-side projections by MFMA (A-fragments from LDS
//   x/h tiles). Layers pipeline with skew 1: block (l,grp) at step t waits
//   cnt[l][grp][t-1]==16 (own h exchange) and cnt[l-1][grp][t]==16 (x ready).
//   All y traffic sc0/sc1 (L3-coherent, bypasses non-coherent L2s).
//   SYNC HARDENING (round 3): the post-store __syncthreads cannot be relied
//   on to drain inline-asm stores (untracked VMEM -> waitcnt pass may omit
//   vmcnt(0)). Producer drain is now an explicit s_waitcnt vmcnt(0) inside
//   the store asm; arrival atomics are RELEASE, spin loads ACQUIRE (agent).
//   y3 aliases act: layer0 reads act[t] strictly before layer3 writes y3[t]
//   (enforced transitively by the counter chain), so the buffers can share
//   storage.
// ---------------------------------------------------------------------------
__device__ inline float u2f(unsigned u) { union { unsigned u; float f; } c; c.u = u; return c.f; }
__device__ inline float sigm(float x) { return 1.f / (1.f + __expf(-x)); }
__device__ inline void spin_ge(unsigned* p, unsigned v)
{
    while (__hip_atomic_load(p, __ATOMIC_ACQUIRE, __HIP_MEMORY_SCOPE_AGENT) < v)
        __builtin_amdgcn_s_sleep(2);
}

__global__ __launch_bounds__(384)
void gru_fused(__hip_bfloat16* __restrict__ act,        // x-in L0 / y3-out
               __hip_bfloat16* __restrict__ ybuf,       // y0,y1,y2
               const __hip_bfloat16* __restrict__ wihb, // [4][1536][512] bf16
               const __hip_bfloat16* __restrict__ whhb, // [4][1536][512] bf16
               const float* __restrict__ bihf,          // [4][1536]
               const float* __restrict__ bhhf,          // [4][1536]
               unsigned* __restrict__ bar)              // [4 layer][4 grp][1024 t]
{
    constexpr int LROW = 1040;                // bytes per LDS tile row (512*2 + 16)
    constexpr size_t YELL = (size_t)64 * 1024 * 512;   // elems per y buffer

    __shared__ __align__(16) char hsl[16 * LROW];
    __shared__ __align__(16) char xsl[16 * LROW];
    __shared__ float ghl[4][16][35];          // r, z, i_n, h_n

    const int tid  = threadIdx.x;
    const int wv   = tid >> 6;
    const int lane = tid & 63;
    const int quad = lane >> 4;
    const int l16  = lane & 15;
    const int layer = blockIdx.x >> 6;
    const int grp   = (blockIdx.x >> 4) & 3;
    const int slc   = blockIdx.x & 15;
    const int j0 = slc * 32;
    const int m0 = grp * 16;
    const int g  = wv >> 1;                   // gate 0..2
    const int jt = wv & 1;

    const __hip_bfloat16* in_l = (layer == 0) ? act : ybuf + (size_t)(layer - 1) * YELL;
    __hip_bfloat16* out_l = (layer == 3) ? act : ybuf + (size_t)layer * YELL;
    const __hip_bfloat16* wih_l = wihb + (size_t)layer * 1536 * 512;
    const __hip_bfloat16* whh_l = whhb + (size_t)layer * 1536 * 512;
    const float* bih_l = bihf + layer * 1536;
    const float* bhh_l = bhhf + layer * 1536;
    unsigned* own = bar + (layer * 4 + grp) * 1024;
    unsigned* prv = (layer > 0) ? bar + ((layer - 1) * 4 + grp) * 1024 : bar;

    // weight fragments, VGPR-resident for all 1024 steps (128 VGPRs/wave)
    const int colg = g * 512 + j0 + jt * 16;
    bf16x8 bX[16], bH[16];
#pragma unroll
    for (int kc = 0; kc < 16; ++kc) {
        bX[kc] = *(const bf16x8*)(wih_l + (size_t)(colg + l16) * 512 + kc * 32 + quad * 8);
        bH[kc] = *(const bf16x8*)(whh_l + (size_t)(colg + l16) * 512 + kc * 32 + quad * 8);
    }

    // zero h state (t=0 computes h-side on zeros -> bias-only, matches ref)
    for (int c = tid; c < 16 * LROW / 16; c += 384)
        ((i32x4*)hsl)[c] = (i32x4)0;

    // combine setup (tid<256): 1 row x 2 cols per thread
    const int row = tid >> 4;                 // 0..15
    const int jp  = tid & 15;
    const int jg  = j0 + 2 * jp;
    float brA = 0, brB = 0, bzA = 0, bzB = 0, biA = 0, biB = 0, bhA = 0, bhB = 0;
    __hip_bfloat16* ysp = nullptr;
    int hofc = 0;
    if (tid < 256) {
        brA = bih_l[jg]        + bhh_l[jg];
        brB = bih_l[jg + 1]    + bhh_l[jg + 1];
        bzA = bih_l[512 + jg]     + bhh_l[512 + jg];
        bzB = bih_l[512 + jg + 1] + bhh_l[512 + jg + 1];
        biA = bih_l[1024 + jg];     biB = bih_l[1024 + jg + 1];
        bhA = bhh_l[1024 + jg];     bhB = bhh_l[1024 + jg + 1];
        ysp  = out_l + (size_t)(m0 + row) * 1024 * 512 + jg;
        hofc = row * LROW + jg * 2;
    }

    // refill setup (tid<256): 4 h-chunks + 4 x-chunks of 16B
    const int mr  = tid >> 6;
    const int bof = (tid & 63) * 16;
    const char* hre[4];
    const char* xre[4];
    int dst[4];
    if (tid < 256) {
#pragma unroll
        for (int q = 0; q < 4; ++q) {
            const int m = mr + q * 4;
            hre[q] = (const char*)out_l + (size_t)(m0 + m) * 1048576 + bof;
            xre[q] = (const char*)in_l  + (size_t)(m0 + m) * 1048576 + bof;
            dst[q] = m * LROW + bof;
        }
    }

    const int abase = l16 * LROW + quad * 16;

    // prologue: wait for x_0 (layers>0), then stage it into xsl
    if (layer > 0 && tid == 0) spin_ge(prv, 16u);
    __syncthreads();
    if (tid < 256) {
        i32x4 v0, v1, v2, v3;
        asm volatile(
            "global_load_dwordx4 %0, %4, off sc0 sc1\n\t"
            "global_load_dwordx4 %1, %5, off sc0 sc1\n\t"
            "global_load_dwordx4 %2, %6, off sc0 sc1\n\t"
            "global_load_dwordx4 %3, %7, off sc0 sc1\n\t"
            "s_waitcnt vmcnt(0)"
            : "=&v"(v0), "=&v"(v1), "=&v"(v2), "=&v"(v3)
            : "v"((const void*)xre[0]), "v"((const void*)xre[1]),
              "v"((const void*)xre[2]), "v"((const void*)xre[3])
            : "memory");
        *(i32x4*)(xsl + dst[0]) = v0;
        *(i32x4*)(xsl + dst[1]) = v1;
        *(i32x4*)(xsl + dst[2]) = v2;
        *(i32x4*)(xsl + dst[3]) = v3;
        xre[0] += 1024; xre[1] += 1024; xre[2] += 1024; xre[3] += 1024;
    }
    __syncthreads();

#pragma unroll 1
    for (int t = 0; t < 1024; ++t) {
        // --- MFMA: i-gates (x @ Wih^T) and h-gates (h @ Whh^T) ---
        f32x4 aX = {}, aH = {};
#pragma unroll
        for (int kc = 0; kc < 16; ++kc) {
            bf16x8 ax = *(const bf16x8*)(xsl + abase + kc * 64);
            bf16x8 ah = *(const bf16x8*)(hsl + abase + kc * 64);
            aX = __builtin_amdgcn_mfma_f32_16x16x32_bf16(ax, bX[kc], aX, 0, 0, 0);
            aH = __builtin_amdgcn_mfma_f32_16x16x32_bf16(ah, bH[kc], aH, 0, 0, 0);
        }
        if (g < 2) {
#pragma unroll
            for (int rg = 0; rg < 4; ++rg)
                ghl[g][quad * 4 + rg][jt * 16 + l16] = aX[rg] + aH[rg];
        } else {
#pragma unroll
            for (int rg = 0; rg < 4; ++rg) {
                ghl[2][quad * 4 + rg][jt * 16 + l16] = aX[rg];
                ghl[3][quad * 4 + rg][jt * 16 + l16] = aH[rg];
            }
        }
        __syncthreads();

        // --- gate combine + h_t write (device-coherent dword store, with
        //     explicit producer-side drain: do NOT rely on the barrier) ---
        if (tid < 256) {
            const float sr0 = ghl[0][row][2 * jp], sr1 = ghl[0][row][2 * jp + 1];
            const float sz0 = ghl[1][row][2 * jp], sz1 = ghl[1][row][2 * jp + 1];
            const float si0 = ghl[2][row][2 * jp], si1 = ghl[2][row][2 * jp + 1];
            const float sh0 = ghl[3][row][2 * jp], sh1 = ghl[3][row][2 * jp + 1];
            const unsigned hpk = *(const unsigned*)(hsl + hofc);
            const float hp0 = u2f(hpk << 16), hp1 = u2f(hpk & 0xffff0000u);
            const float r0 = sigm(sr0 + brA), r1 = sigm(sr1 + brB);
            const float z0 = sigm(sz0 + bzA), z1 = sigm(sz1 + bzB);
            const float n0 = tanhf(si0 + biA + r0 * (sh0 + bhA));
            const float n1 = tanhf(si1 + biB + r1 * (sh1 + bhB));
            const float h0 = (1.f - z0) * n0 + z0 * hp0;
            const float h1 = (1.f - z1) * n1 + z1 * hp1;
            const unsigned outv =
                (unsigned)__bfloat16_as_ushort(__float2bfloat16(h0)) |
                ((unsigned)__bfloat16_as_ushort(__float2bfloat16(h1)) << 16);
            asm volatile("global_store_dword %0, %1, off sc0 sc1\n\t"
                         "s_waitcnt vmcnt(0)"
                         :: "v"((void*)ysp), "v"(outv) : "memory");
            ysp += 512;
        }
        __syncthreads();

        // --- arrival + pipeline waits (single thread, then broadcast) ---
        if (tid == 0) {
            __hip_atomic_fetch_add(&own[t], 1u, __ATOMIC_RELEASE, __HIP_MEMORY_SCOPE_AGENT);
            if (t < 1023) {
                spin_ge(&own[t], 16u);                      // h_t fully exchanged
                if (layer > 0) spin_ge(&prv[t + 1], 16u);   // x_{t+1} ready
            }
        }
        __syncthreads();

        // --- refill LDS h_t and x_{t+1} (device-coherent b128 loads) ---
        if (t < 1023) {
            if (tid < 256) {
                i32x4 h0, h1, h2, h3, x0, x1, x2, x3;
                asm volatile(
                    "global_load_dwordx4 %0, %8, off sc0 sc1\n\t"
                    "global_load_dwordx4 %1, %9, off sc0 sc1\n\t"
                    "global_load_dwordx4 %2, %10, off sc0 sc1\n\t"
                    "global_load_dwordx4 %3, %11, off sc0 sc1\n\t"
                    "global_load_dwordx4 %4, %12, off sc0 sc1\n\t"
                    "global_load_dwordx4 %5, %13, off sc0 sc1\n\t"
                    "global_load_dwordx4 %6, %14, off sc0 sc1\n\t"
                    "global_load_dwordx4 %7, %15, off sc0 sc1\n\t"
                    "s_waitcnt vmcnt(0)"
                    : "=&v"(h0), "=&v"(h1), "=&v"(h2), "=&v"(h3),
                      "=&v"(x0), "=&v"(x1), "=&v"(x2), "=&v"(x3)
                    : "v"((const void*)hre[0]), "v"((const void*)hre[1]),
                      "v"((const void*)hre[2]), "v"((const void*)hre[3]),
                      "v"((const void*)xre[0]), "v"((const void*)xre[1]),
                      "v"((const void*)xre[2]), "v"((const void*)xre[3])
                    : "memory");
                *(i32x4*)(hsl + dst[0]) = h0;
                *(i32x4*)(hsl + dst[1]) = h1;
                *(i32x4*)(hsl + dst[2]) = h2;
                *(i32x4*)(hsl + dst[3]) = h3;
                *(i32x4*)(xsl + dst[0]) = x0;
                *(i32x4*)(xsl + dst[1]) = x1;
                *(i32x4*)(xsl + dst[2]) = x2;
                *(i32x4*)(xsl + dst[3]) = x3;
                hre[0] += 1024; hre[1] += 1024; hre[2] += 1024; hre[3] += 1024;
                xre[0] += 1024; xre[1] += 1024; xre[2] += 1024; xre[3] += 1024;
            }
            __syncthreads();
        }
    }
}

// ---------------------------------------------------------------------------
// Host-side launch
// ---------------------------------------------------------------------------
extern "C" void kernel_launch(void* const* d_in, const int* in_sizes, int n_in,
                              void* d_out, int out_size, void* d_ws, size_t ws_size,
                              hipStream_t stream)
{
    const float* x    = (const float*)d_in[0];
    const float* w_in = (const float*)d_in[1];
    const float* b_in = (const float*)d_in[2];
    const float* w_ih = (const float*)d_in[3];
    const float* w_hh = (const float*)d_in[4];
    const float* b_ih = (const float*)d_in[5];
    const float* b_hh = (const float*)d_in[6];
    const float* w_o1 = (const float*)d_in[7];
    const float* b_o1 = (const float*)d_in[8];
    const float* w_o2 = (const float*)d_in[9];
    const float* b_o2 = (const float*)d_in[10];
    float* out = (float*)d_out;

    char* ws = (char*)d_ws;
    const size_t YB_BYTES  = (size_t)BT_N * 512 * 2;   //  67,108,864 (one y buffer)
    const size_t GI_BYTES  = 3 * YB_BYTES;             // 201,326,592 (y0,y1,y2)
    const size_t WT_BYTES  = (size_t)7077888 * 2;      //  14,155,776
    __hip_bfloat16* ybuf = (__hip_bfloat16*)ws;                       // y0,y1,y2
    __hip_bfloat16* act  = (__hip_bfloat16*)(ws + GI_BYTES);          // L0-in / y3-out
    __hip_bfloat16* wbf  = (__hip_bfloat16*)(ws + GI_BYTES + YB_BYTES);
    unsigned*       bar  = (unsigned*)(ws + GI_BYTES + YB_BYTES + WT_BYTES); // 64 KiB
    __hip_bfloat16* xbf  = ybuf;   // alias: dead before y0 written
    __hip_bfloat16* tmp  = ybuf;   // alias: MLP intermediate (y0 dead post-scan)

    __hip_bfloat16* w_in_bf = wbf;
    __hip_bfloat16* w_ih_bf = wbf + 262144;
    __hip_bfloat16* w_hh_bf = w_ih_bf + 3145728;
    __hip_bfloat16* w_o1_bf = w_hh_bf + 3145728;
    __hip_bfloat16* w_o2_bf = w_o1_bf + 262144;

    // pipeline arrival counters: [4 layers][4 groups][1024 t]
    hipMemsetAsync(bar, 0, (size_t)4 * 4 * 1024 * sizeof(unsigned), stream);

    cvt_f32_bf16<<<256, 256, 0, stream>>>(w_in, w_in_bf, 262144 / 4);
    cvt_f32_bf16<<<1024, 256, 0, stream>>>(w_ih, w_ih_bf, 3145728 / 4);
    cvt_f32_bf16<<<1024, 256, 0, stream>>>(w_hh, w_hh_bf, 3145728 / 4);
    cvt_f32_bf16<<<256, 256, 0, stream>>>(w_o1, w_o1_bf, 262144 / 4);
    cvt_f32_bf16<<<256, 256, 0, stream>>>(w_o2, w_o2_bf, 262144 / 4);
    cvt_f32_bf16<<<4096, 256, 0, stream>>>(x, xbf, BT_N * 512 / 4);

    const int M = (int)BT_N;

    // input linear + ReLU -> act (bf16)
    mfma_gemm<__hip_bfloat16, true><<<dim3(4, 512), 256, 0, stream>>>(
        xbf, w_in_bf, b_in, act, M, 512, 512);

    // all 4 GRU layers, pipelined with skew 1, in a single launch
    gru_fused<<<dim3(256), dim3(384), 0, stream>>>(
        act, ybuf, w_ih_bf, w_hh_bf, b_ih, b_hh, bar);

    // output MLP: act(y3) -> tmp (relu, bf16) -> out (fp32)
    mfma_gemm<__hip_bfloat16, true><<<dim3(4, 512), 256, 0, stream>>>(
        act, w_o1_bf, b_o1, tmp, M, 512, 512);
    mfma_gemm<float, false><<<dim3(4, 512), 256, 0, stream>>>(
        tmp, w_o2_bf, b_o2, out, M, 512, 512);
}